// Round 1
// baseline (58.162 us; speedup 1.0000x reference)
//
#include <hip/hip_runtime.h>
#include <math.h>

#define HDIM 2048          // hidden size H (== D_IN)
#define DOUT 1024
#define CELLS_PER_BLOCK 2  // each block produces 2 h-cells (8 gate rows)

__device__ __forceinline__ float sigmoidf_(float x) {
    return 1.0f / (1.0f + expf(-x));
}

// One LSTM layer, single timestep, batch=1.
// grid = HDIM/CELLS_PER_BLOCK blocks, 256 threads (4 waves).
// Wave w computes gate w (i,f,g,o) for both cells of the block.
__launch_bounds__(256)
__global__ void lstm_layer_k(const float* __restrict__ Wi,   // [4H, H]
                             const float* __restrict__ Wh,   // [4H, H]
                             const float* __restrict__ bi,   // [4H]
                             const float* __restrict__ bh,   // [4H]
                             const float* __restrict__ hin,  // [H]
                             const float* __restrict__ hprev,// [H]
                             const float* __restrict__ cprev,// [H]
                             float* __restrict__ hout)       // [H]
{
    __shared__ float4 sh_in[HDIM / 4];    // 8 KiB
    __shared__ float4 sh_prev[HDIM / 4];  // 8 KiB
    __shared__ float  sgates[4 * CELLS_PER_BLOCK];
    __shared__ int    nzflag;

    const int tid = threadIdx.x;
    if (tid == 0) nzflag = 0;
    __syncthreads();

    // Stage h_in and h_prev into LDS; detect whether h_prev has any nonzero.
    int nz = 0;
#pragma unroll
    for (int i = 0; i < (HDIM / 4) / 256; ++i) {
        const int idx = tid + i * 256;
        float4 v = ((const float4*)hin)[idx];
        sh_in[idx] = v;
        float4 p = ((const float4*)hprev)[idx];
        sh_prev[idx] = p;
        if (p.x != 0.0f || p.y != 0.0f || p.z != 0.0f || p.w != 0.0f) nz = 1;
    }
    if (nz) nzflag = 1;  // benign race: all writers store 1
    __syncthreads();
    const int any_prev = nzflag;  // block-uniform after barrier

    const int lane = tid & 63;
    const int wave = tid >> 6;               // == gate index (i,f,g,o)
    const int cell0 = blockIdx.x * CELLS_PER_BLOCK;
    const int row0 = wave * HDIM + cell0;    // row in the [4H, H] matrix

    const float4* r0 = (const float4*)(Wi + (size_t)row0 * HDIM);
    const float4* r1 = (const float4*)(Wi + (size_t)(row0 + 1) * HDIM);

    float acc0 = 0.0f, acc1 = 0.0f;
#pragma unroll
    for (int it = 0; it < HDIM / 256; ++it) {
        const int idx = it * 64 + lane;
        const float4 a0 = r0[idx];
        const float4 a1 = r1[idx];
        const float4 hv = sh_in[idx];
        acc0 = fmaf(a0.x, hv.x, fmaf(a0.y, hv.y, fmaf(a0.z, hv.z, fmaf(a0.w, hv.w, acc0))));
        acc1 = fmaf(a1.x, hv.x, fmaf(a1.y, hv.y, fmaf(a1.z, hv.z, fmaf(a1.w, hv.w, acc1))));
    }

    if (any_prev) {  // only touch W_hh when h_prev is not identically zero
        const float4* q0 = (const float4*)(Wh + (size_t)row0 * HDIM);
        const float4* q1 = (const float4*)(Wh + (size_t)(row0 + 1) * HDIM);
#pragma unroll
        for (int it = 0; it < HDIM / 256; ++it) {
            const int idx = it * 64 + lane;
            const float4 a0 = q0[idx];
            const float4 a1 = q1[idx];
            const float4 pv = sh_prev[idx];
            acc0 = fmaf(a0.x, pv.x, fmaf(a0.y, pv.y, fmaf(a0.z, pv.z, fmaf(a0.w, pv.w, acc0))));
            acc1 = fmaf(a1.x, pv.x, fmaf(a1.y, pv.y, fmaf(a1.z, pv.z, fmaf(a1.w, pv.w, acc1))));
        }
    }

    // 64-lane reduction
#pragma unroll
    for (int off = 32; off > 0; off >>= 1) {
        acc0 += __shfl_down(acc0, off, 64);
        acc1 += __shfl_down(acc1, off, 64);
    }
    if (lane == 0) {
        sgates[wave * CELLS_PER_BLOCK + 0] = acc0 + bi[row0] + bh[row0];
        sgates[wave * CELLS_PER_BLOCK + 1] = acc1 + bi[row0 + 1] + bh[row0 + 1];
    }
    __syncthreads();

    if (tid < CELLS_PER_BLOCK) {
        const float iv = sgates[0 * CELLS_PER_BLOCK + tid];
        const float fv = sgates[1 * CELLS_PER_BLOCK + tid];
        const float gv = sgates[2 * CELLS_PER_BLOCK + tid];
        const float ov = sgates[3 * CELLS_PER_BLOCK + tid];
        const float cp = cprev[cell0 + tid];
        const float cv = sigmoidf_(fv) * cp + sigmoidf_(iv) * tanhf(gv);
        const float hv = sigmoidf_(ov) * tanhf(cv);
        hout[cell0 + tid] = hv;
    }
}

// out[DOUT] = W[DOUT,H] @ h + b. grid = DOUT/4 blocks, 256 threads; 1 row/wave.
__launch_bounds__(256)
__global__ void fc_k(const float* __restrict__ W, const float* __restrict__ b,
                     const float* __restrict__ h, float* __restrict__ out)
{
    __shared__ float4 sh[HDIM / 4];
    const int tid = threadIdx.x;
#pragma unroll
    for (int i = 0; i < (HDIM / 4) / 256; ++i)
        sh[tid + i * 256] = ((const float4*)h)[tid + i * 256];
    __syncthreads();

    const int lane = tid & 63;
    const int wave = tid >> 6;
    const int row = blockIdx.x * 4 + wave;

    const float4* r = (const float4*)(W + (size_t)row * HDIM);
    float acc = 0.0f;
#pragma unroll
    for (int it = 0; it < HDIM / 256; ++it) {
        const int idx = it * 64 + lane;
        const float4 a = r[idx];
        const float4 hv = sh[idx];
        acc = fmaf(a.x, hv.x, fmaf(a.y, hv.y, fmaf(a.z, hv.z, fmaf(a.w, hv.w, acc))));
    }
#pragma unroll
    for (int off = 32; off > 0; off >>= 1) acc += __shfl_down(acc, off, 64);
    if (lane == 0) out[row] = acc + b[row];
}

extern "C" void kernel_launch(void* const* d_in, const int* in_sizes, int n_in,
                              void* d_out, int out_size, void* d_ws, size_t ws_size,
                              hipStream_t stream) {
    const float* x    = (const float*)d_in[0];  // [2048]
    const float* h0   = (const float*)d_in[1];  // [4,1,2048]
    const float* c0   = (const float*)d_in[2];  // [4,1,2048]
    const float* Wih  = (const float*)d_in[3];  // [4, 8192, 2048]
    const float* Whh  = (const float*)d_in[4];  // [4, 8192, 2048]
    const float* bih  = (const float*)d_in[5];  // [4, 8192]
    const float* bhh  = (const float*)d_in[6];  // [4, 8192]
    const float* fcw  = (const float*)d_in[7];  // [1024, 2048]
    const float* fcb  = (const float*)d_in[8];  // [1024]
    float* out = (float*)d_out;

    float* hb0 = (float*)d_ws;          // ping
    float* hb1 = hb0 + HDIM;            // pong

    const size_t wstride = (size_t)4 * HDIM * HDIM;  // per-layer weight stride
    const int    bstride = 4 * HDIM;

    const float* hin = x;
    float* houts[4] = {hb0, hb1, hb0, hb1};
    for (int l = 0; l < 4; ++l) {
        lstm_layer_k<<<HDIM / CELLS_PER_BLOCK, 256, 0, stream>>>(
            Wih + (size_t)l * wstride, Whh + (size_t)l * wstride,
            bih + l * bstride, bhh + l * bstride,
            hin, h0 + l * HDIM, c0 + l * HDIM, houts[l]);
        hin = houts[l];
    }
    fc_k<<<DOUT / 4, 256, 0, stream>>>(fcw, fcb, hb1, out);
}